// Round 16
// baseline (175.070 us; speedup 1.0000x reference)
//
#include <hip/hip_runtime.h>
#include <hip/hip_bf16.h>
#include <cstdint>
#include <cstddef>

// Problem constants
#define Bb 4
#define Ss 2048
#define Dd 1024
#define Hh 16
#define Mm (Bb*Ss)   // 8192 rows

typedef __bf16 bf16_t;
typedef __bf16 bf16x8 __attribute__((ext_vector_type(8)));
typedef __bf16 bf16x4 __attribute__((ext_vector_type(4)));
typedef float  f32x4  __attribute__((ext_vector_type(4)));
typedef float  f32x16 __attribute__((ext_vector_type(16)));
typedef unsigned int u32x4 __attribute__((ext_vector_type(4)));
typedef unsigned int u32x2 __attribute__((ext_vector_type(2)));

#define MFMA16(a,b,c) __builtin_amdgcn_mfma_f32_16x16x32_bf16(a,b,c,0,0,0)
#define MFMA32(a,b,c) __builtin_amdgcn_mfma_f32_32x32x16_bf16(a,b,c,0,0,0)

#define QSCALE 0.18033688011112042f   // 0.125 * log2(e): exp2-domain softmax

static __device__ __forceinline__ float fexp2(float x) {
#if __has_builtin(__builtin_amdgcn_exp2f)
  return __builtin_amdgcn_exp2f(x);
#else
  return exp2f(x);
#endif
}

static __device__ __forceinline__ bf16x8 ld16g(const bf16_t* p) {
  return __builtin_bit_cast(bf16x8, *reinterpret_cast<const u32x4*>(p));
}

static __device__ __forceinline__ void gload_lds16(const bf16_t* g, bf16_t* l) {
  __builtin_amdgcn_global_load_lds(
      (__attribute__((address_space(1))) void*)(g),
      (__attribute__((address_space(3))) void*)(l),
      16, 0, 0);
}

// ---------- unified prep: x->bf16, weights->bf16 block, RoPE table ----------
// blocks [0,8192): x convert; [8192,12288): weight convert; [12288,12544): tab
__global__ void prep_k(const float* __restrict__ x,  const float* __restrict__ wq,
                       const float* __restrict__ wk, const float* __restrict__ wv,
                       const float* __restrict__ wo,
                       bf16_t* __restrict__ xb, bf16_t* __restrict__ wqkv,
                       float2* __restrict__ tab) {
  int bid = blockIdx.x;
  if (bid < 8192) {
    int i = (bid * 256 + threadIdx.x) * 4;
    float4 f = *reinterpret_cast<const float4*>(x + i);
    xb[i + 0] = (bf16_t)f.x; xb[i + 1] = (bf16_t)f.y;
    xb[i + 2] = (bf16_t)f.z; xb[i + 3] = (bf16_t)f.w;
  } else if (bid < 12288) {
    int b2 = bid - 8192;
    int seg = b2 >> 10, local = b2 & 1023;
    const float* w = (seg == 0) ? wq : (seg == 1) ? wk : (seg == 2) ? wv : wo;
    int i = (local * 256 + threadIdx.x) * 4;
    float4 f = *reinterpret_cast<const float4*>(w + i);
    bf16_t* o = wqkv + (size_t)seg * (Dd * Dd) + i;
    o[0] = (bf16_t)f.x; o[1] = (bf16_t)f.y; o[2] = (bf16_t)f.z; o[3] = (bf16_t)f.w;
  } else {
    int idx = (bid - 12288) * 256 + threadIdx.x;   // 65536
    int i = idx & 31, s = idx >> 5;
    float inv_freq = exp2f(-(float)i * (13.2877123795494f / 32.0f));
    float ang = (float)s * inv_freq;
    float sn, cs;
    sincosf(ang, &sn, &cs);
    tab[idx] = make_float2(cs, sn);
  }
}

// ------------- GEMM big-tile: C[m][n] = sum_k A[m][k]*B[n][k] ---------------
// BM=BN=256, BK=32, 1024 thr = 16 waves (4M x 4N) of 64x64 each.
// Rationale: all previous structures had FLOP/staged-byte = 32 and pinned at
// ~650 TF = (measured ~33 B/cyc/CU L2 delivery) x 32; this doubles arithmetic
// intensity to 64 while keeping 16 waves/CU (the round-9 best occupancy).
// Ring-2 LDS (64KB); fence = vmcnt(0)+lgkmcnt(0)+s_barrier once per K-step;
// stage(j+1) issued right after barrier j (a full K-step of latency slack --
// the round-15 attn pattern, same race-safety argument). Slot-XOR swizzle
// slot^((row>>1)&3) with inverse-swizzled global source (0 bank conflicts).
// Epilogues: Q (n0<1024): RoPE+QSCALE; K: RoPE; V (n0>=2048): transposed Vt.
__global__ __launch_bounds__(1024, 4) void gemm_big(const bf16_t* __restrict__ A,
                                                    const bf16_t* __restrict__ Bm,
                                                    bf16_t* __restrict__ C0,
                                                    bf16_t* __restrict__ C1,
                                                    bf16_t* __restrict__ VtOut,
                                                    const float2* __restrict__ tab,
                                                    int Kdim) {
  __shared__ bf16_t As[2][256 * 32];   // 32 KB
  __shared__ bf16_t Bs[2][256 * 32];   // 32 KB
  const int t = threadIdx.x;
  const int lane = t & 63, w = t >> 6;          // w 0..15
  const int l15 = lane & 15, lg = lane >> 4;
  const int wm = w >> 2, wn = w & 3;
  const int m0 = blockIdx.x * 256, n0 = blockIdx.y * 256;

  // stage addressing: tile = 256 rows x 32 cols = 1024 16B-chunks, 1/thread.
  // chunk q=t -> row = q>>2, phys slot = q&3, src slot = (q&3)^((row>>1)&3)
  const int row_ = t >> 2, sl_ = (t & 3) ^ ((row_ >> 1) & 3);
  const bf16_t* gA = A  + (size_t)(m0 + row_) * Kdim + sl_ * 8;
  const bf16_t* gB = Bm + (size_t)(n0 + row_) * Kdim + sl_ * 8;
  const int wb = w * 512;   // wave-uniform LDS elem base (lane*16B added by HW)

  auto stage = [&](int buf, int k0) {
    gload_lds16(gA + k0, &As[buf][wb]);
    gload_lds16(gB + k0, &Bs[buf][wb]);
  };

  // fragment read offsets (elems)
  int aoff[4], boff[4];
#pragma unroll
  for (int i = 0; i < 4; ++i) {
    int row = wm * 64 + i * 16 + l15;
    aoff[i] = row * 32 + ((lg ^ ((row >> 1) & 3)) * 8);
  }
#pragma unroll
  for (int j = 0; j < 4; ++j) {
    int row = wn * 64 + j * 16 + l15;
    boff[j] = row * 32 + ((lg ^ ((row >> 1) & 3)) * 8);
  }

  f32x4 acc[4][4] = {};
  const int KT = Kdim / 32;

  stage(0, 0);
  for (int j = 0; j < KT; ++j) {
    asm volatile("s_waitcnt vmcnt(0) lgkmcnt(0)" ::: "memory");
    __builtin_amdgcn_s_barrier();
    if (j + 1 < KT) stage((j + 1) & 1, (j + 1) * 32);
    const bf16_t* ab = As[j & 1];
    const bf16_t* bb = Bs[j & 1];
    bf16x8 a[4], b[4];
#pragma unroll
    for (int jj = 0; jj < 4; ++jj)
      b[jj] = __builtin_bit_cast(bf16x8,
               *reinterpret_cast<const u32x4*>(bb + boff[jj]));
#pragma unroll
    for (int i = 0; i < 4; ++i)
      a[i] = __builtin_bit_cast(bf16x8,
               *reinterpret_cast<const u32x4*>(ab + aoff[i]));
    __builtin_amdgcn_s_setprio(1);
#pragma unroll
    for (int i = 0; i < 4; ++i)
#pragma unroll
      for (int jj = 0; jj < 4; ++jj)
        acc[i][jj] = MFMA16(a[i], b[jj], acc[i][jj]);
    __builtin_amdgcn_s_setprio(0);
  }

  // epilogue: row = m0 + wm*64 + i*16 + lg*4 + r; col = n0 + wn*64 + j*16 + l15
  const int nb = n0 & 1023;
  if (VtOut != nullptr && n0 >= 2048) {
    // V segment: transposed write Vt[(b*16+h)*64 + d][s], s = row & 2047
#pragma unroll
    for (int i = 0; i < 4; ++i) {
      int rowb = m0 + wm * 64 + i * 16 + lg * 4;
      int b = rowb >> 11, s = rowb & 2047;
#pragma unroll
      for (int j = 0; j < 4; ++j) {
        int col = nb + wn * 64 + j * 16 + l15;
        int h = col >> 6, d = col & 63;
        bf16x4 ov;
#pragma unroll
        for (int r = 0; r < 4; ++r) ov[r] = (bf16_t)acc[i][j][r];
        *reinterpret_cast<u32x2*>(
            &VtOut[(((size_t)(b * 16 + h)) * 64 + d) * 2048 + s]) =
            __builtin_bit_cast(u32x2, ov);
      }
    }
    return;
  }
  bf16_t* Cs = (n0 < 1024) ? C0 : C1;
  const float qs = (n0 < 1024) ? QSCALE : 1.0f;
#pragma unroll
  for (int i = 0; i < 4; ++i) {
    int rowb = m0 + wm * 64 + i * 16 + lg * 4;
#pragma unroll
    for (int j = 0; j < 4; ++j) {
      int col = nb + wn * 64 + j * 16 + l15;
      int i0 = (col & 63) >> 1;
      const bool ev = !(col & 1);
#pragma unroll
      for (int r = 0; r < 4; ++r) {
        float v = acc[i][j][r];
        float px = __shfl_xor(v, 1);
        int s = (rowb + r) & (Ss - 1);
        float2 f = tab[s * 32 + i0];
        float sn = ev ? -f.y : f.y;
        Cs[(size_t)(rowb + r) * 1024 + col] = (bf16_t)((f.x * v + sn * px) * qs);
      }
    }
  }
}

// ---------------- GEMM ring3 (out-projection): fp32 out ---------------------
// 128x128 tile, BK=32, 256 thr = 4 waves, 48KB ring-3 -> 3 blocks/CU; counted
// fence vmcnt(4)+lgkmcnt(0)+s_barrier; slot-XOR swizzle. (Round-14 config.)
__global__ __launch_bounds__(256, 3) void gemm_r3(const bf16_t* __restrict__ A,
                                                  const bf16_t* __restrict__ Bm,
                                                  float* __restrict__ C0,
                                                  int Kdim) {
  __shared__ bf16_t As[3][128 * 32];   // 24 KB
  __shared__ bf16_t Bs[3][128 * 32];   // 24 KB
  const int t = threadIdx.x;
  const int lane = t & 63, w = t >> 6;
  const int l15 = lane & 15, lg = lane >> 4;
  const int wr = w >> 1, wc = w & 1;
  const int m0 = blockIdx.x * 128, n0 = blockIdx.y * 128;

  const bf16_t* gA[2];
  const bf16_t* gB[2];
#pragma unroll
  for (int i = 0; i < 2; ++i) {
    int q = i * 256 + t, row = q >> 2, sl = (q & 3) ^ ((row >> 1) & 3);
    gA[i] = A  + (size_t)(m0 + row) * Kdim + sl * 8;
    gB[i] = Bm + (size_t)(n0 + row) * Kdim + sl * 8;
  }
  const int wb = w * 64 * 8;

  auto stage = [&](int slot, int k0) {
#pragma unroll
    for (int i = 0; i < 2; ++i) {
      gload_lds16(gA[i] + k0, &As[slot][i * 2048 + wb]);
      gload_lds16(gB[i] + k0, &Bs[slot][i * 2048 + wb]);
    }
  };

  int aoff[4], boff[4];
#pragma unroll
  for (int i = 0; i < 4; ++i) {
    int row = wr * 64 + i * 16 + l15;
    aoff[i] = row * 32 + ((lg ^ ((row >> 1) & 3)) * 8);
  }
#pragma unroll
  for (int j = 0; j < 4; ++j) {
    int row = wc * 64 + j * 16 + l15;
    boff[j] = row * 32 + ((lg ^ ((row >> 1) & 3)) * 8);
  }

  f32x4 acc[4][4] = {};
  const int KT = Kdim / 32;

  stage(0, 0);
  stage(1, 32);
  for (int j = 0; j < KT; ++j) {
    if (j == KT - 1) {
      asm volatile("s_waitcnt vmcnt(0) lgkmcnt(0)" ::: "memory");
    } else {
      asm volatile("s_waitcnt vmcnt(4) lgkmcnt(0)" ::: "memory");
    }
    __builtin_amdgcn_s_barrier();
    if (j + 2 < KT) stage((j + 2) % 3, (j + 2) * 32);
    const bf16_t* ab = As[j % 3];
    const bf16_t* bb = Bs[j % 3];
    bf16x8 a[4], b[4];
#pragma unroll
    for (int jj = 0; jj < 4; ++jj)
      b[jj] = __builtin_bit_cast(bf16x8,
               *reinterpret_cast<const u32x4*>(bb + boff[jj]));
#pragma unroll
    for (int i = 0; i < 4; ++i)
      a[i] = __builtin_bit_cast(bf16x8,
               *reinterpret_cast<const u32x4*>(ab + aoff[i]));
    __builtin_amdgcn_s_setprio(1);
#pragma unroll
    for (int i = 0; i < 4; ++i)
#pragma unroll
      for (int jj = 0; jj < 4; ++jj)
        acc[i][jj] = MFMA16(a[i], b[jj], acc[i][jj]);
    __builtin_amdgcn_s_setprio(0);
  }

#pragma unroll
  for (int i = 0; i < 4; ++i) {
    int rowb = m0 + wr * 64 + i * 16 + lg * 4;
#pragma unroll
    for (int j = 0; j < 4; ++j) {
      int col = n0 + wc * 64 + j * 16 + l15;
#pragma unroll
      for (int r = 0; r < 4; ++r)
        C0[(size_t)(rowb + r) * 1024 + col] = acc[i][j][r];
    }
  }
}

// ---------------- Flash attention (causal, static softmax, KVBLK=128) -------
// grid (8, B*H), 256 thr = 4 waves. Wave i = bx*4+w handles q-chunks 32*i and
// 2016-32*i. K/V staged per 128-key tile into a ring-2 LDS (64KB); fence =
// vmcnt(0)+lgkmcnt(0)+s_barrier once per 128 keys (drained loads issued a
// full iteration earlier). STATIC softmax (p = exp2(s') directly). Swapped
// QK^T with sigma-permuted K rows keeps P in-register feeding PV.
__global__ __launch_bounds__(256, 2) void attn_k(const bf16_t* __restrict__ Q,
                                                 const bf16_t* __restrict__ K,
                                                 const bf16_t* __restrict__ Vt,
                                                 bf16_t* __restrict__ O) {
  __shared__ bf16_t Ks[2][8192];   // [buf][4 subtiles x 16 rows x 128 elems]
  __shared__ bf16_t Vs[2][8192];
  const int t = threadIdx.x, lane = t & 63, w = t >> 6;
  const int l31 = lane & 31, hi = lane >> 5, hi8 = hi * 8;
  const int bh = blockIdx.y, b = bh >> 4, h = bh & 15;
  const int bx = blockIdx.x;
  const int i = bx * 4 + w;                      // 0..31
  const int q0a = 32 * i, q0b = 2016 - 32 * i;
  const int dtA = q0a >> 6, hfA = (q0a >> 5) & 1;
  const int dtB = q0b >> 6, hfB = (q0b >> 5) & 1;
  const int NT2 = 16 - bx;                       // 128-key iterations
  const bf16_t* qb = Q + (size_t)b * Ss * Dd + h * 64;
  const bf16_t* kb = K + (size_t)b * Ss * Dd + h * 64;
  const bf16_t* vtb = Vt + (size_t)bh * 64 * Ss;

  const int a_ = l31 >> 2, c_ = l31 & 3;
  const int tau = (a_ >> 1) + 2 * (a_ & 1) + ((a_ & 4) >> 1);
  const int sig = c_ + 4 * tau;

  int kfoff[4];
#pragma unroll
  for (int c = 0; c < 4; ++c) {
    int j = sig >> 1, u = (sig & 1) * 8 + c * 2 + hi;
    kfoff[c] = j * 128 + ((u ^ j) * 8);
  }
  int vfoff[2][2];
#pragma unroll
  for (int db = 0; db < 2; ++db)
#pragma unroll
    for (int ks = 0; ks < 2; ++ks) {
      int d = db * 32 + l31, j = d >> 2, u = (d & 3) * 4 + ks * 2 + hi;
      vfoff[db][ks] = j * 128 + ((u ^ j) * 8);
    }

  const int sj = t >> 4, ss = t & 15, su = ss ^ sj;
  const bf16_t* ksrc0 = kb + (size_t)(2 * sj + (su >> 3)) * Dd + (su & 7) * 8;
  const bf16_t* vsrc0 = vtb + (size_t)(4 * sj + (su >> 2)) * Ss + (su & 3) * 8;

  auto stage128 = [&](int buf, int kb0) {
    bf16_t* kd = &Ks[buf][w * 512];
    bf16_t* vd = &Vs[buf][w * 512];
#pragma unroll
    for (int st = 0; st < 4; ++st) {
      gload_lds16(ksrc0 + (size_t)(kb0 + 32 * st) * Dd, kd + st * 2048);
      gload_lds16(vsrc0 + kb0 + 32 * st,                vd + st * 2048);
    }
  };

  bf16x8 qf[2][4];
#pragma unroll
  for (int c = 0; c < 4; ++c) {
    qf[0][c] = ld16g(qb + (size_t)(q0a + l31) * Dd + c * 16 + hi8);
    qf[1][c] = ld16g(qb + (size_t)(q0b + l31) * Dd + c * 16 + hi8);
  }

  float l_[2] = {0.f, 0.f};
  f32x16 o_[2][2] = {};

  auto chain = [&](int kt, int dt, int hf, bf16x8 (&qc)[4],
                   f32x16& o0, f32x16& o1, float& lc,
                   bf16x8 (&kf)[2][4], bf16x8 (&vf)[2][2][2]) {
    if (kt > dt) return;
    const bool last = (kt == dt);
    const bool do1 = !(last && hf == 0);
    f32x16 s0 = {}, s1 = {};
    __builtin_amdgcn_s_setprio(1);
    s0 = MFMA32(kf[0][0], qc[0], s0);
    s0 = MFMA32(kf[0][1], qc[1], s0);
    s0 = MFMA32(kf[0][2], qc[2], s0);
    s0 = MFMA32(kf[0][3], qc[3], s0);
    if (do1) {
      s1 = MFMA32(kf[1][0], qc[0], s1);
      s1 = MFMA32(kf[1][1], qc[1], s1);
      s1 = MFMA32(kf[1][2], qc[2], s1);
      s1 = MFMA32(kf[1][3], qc[3], s1);
    }
    __builtin_amdgcn_s_setprio(0);
    if (last) {
      if (hf) {
#pragma unroll
        for (int reg = 0; reg < 16; ++reg) {
          const int koff = (reg & 3) + 4 * (reg >> 2) + 8 * ((reg >> 2) >> 1) + hi8;
          s1[reg] = (koff <= l31) ? s1[reg] : -INFINITY;
        }
      } else {
#pragma unroll
        for (int reg = 0; reg < 16; ++reg) {
          const int koff = (reg & 3) + 4 * (reg >> 2) + 8 * ((reg >> 2) >> 1) + hi8;
          s0[reg] = (koff <= l31) ? s0[reg] : -INFINITY;
        }
      }
    }
    float p0[16], p1[16];
#pragma unroll
    for (int r = 0; r < 16; ++r) p0[r] = fexp2(s0[r]);
    bf16x8 pa0, pa1, pb0, pb1;
#pragma unroll
    for (int r = 0; r < 8; ++r) { pa0[r] = (bf16_t)p0[r]; pa1[r] = (bf16_t)p0[r + 8]; }
    if (do1) {
#pragma unroll
      for (int r = 0; r < 16; ++r) p1[r] = fexp2(s1[r]);
#pragma unroll
      for (int r = 0; r < 8; ++r) { pb0[r] = (bf16_t)p1[r]; pb1[r] = (bf16_t)p1[r + 8]; }
#pragma unroll
      for (int r = 0; r < 16; ++r) p0[r] += p1[r];
    }
#pragma unroll
    for (int st2 = 8; st2 > 0; st2 >>= 1)
#pragma unroll
      for (int r = 0; r < st2; ++r) p0[r] += p0[r + st2];
    lc += p0[0];
    __builtin_amdgcn_s_setprio(1);
    o0 = MFMA32(vf[0][0][0], pa0, o0);
    o0 = MFMA32(vf[0][0][1], pa1, o0);
    o1 = MFMA32(vf[0][1][0], pa0, o1);
    o1 = MFMA32(vf[0][1][1], pa1, o1);
    if (do1) {
      o0 = MFMA32(vf[1][0][0], pb0, o0);
      o0 = MFMA32(vf[1][0][1], pb1, o0);
      o1 = MFMA32(vf[1][1][0], pb0, o1);
      o1 = MFMA32(vf[1][1][1], pb1, o1);
    }
    __builtin_amdgcn_s_setprio(0);
  };

  stage128(0, 0);
  for (int jj = 0; jj < NT2; ++jj) {
    asm volatile("s_waitcnt vmcnt(0) lgkmcnt(0)" ::: "memory");
    __builtin_amdgcn_s_barrier();
    if (jj + 1 < NT2) stage128((jj + 1) & 1, (jj + 1) * 128);
    const bf16_t* kbuf = &Ks[jj & 1][0];
    const bf16_t* vbuf = &Vs[jj & 1][0];
#pragma unroll
    for (int half = 0; half < 2; ++half) {
      const int kt = 2 * jj + half;
      const int base = half * 4096;
      bf16x8 kf[2][4], vf[2][2][2];
#pragma unroll
      for (int st = 0; st < 2; ++st)
#pragma unroll
        for (int c = 0; c < 4; ++c)
          kf[st][c] = __builtin_bit_cast(bf16x8,
              *reinterpret_cast<const u32x4*>(kbuf + base + st * 2048 + kfoff[c]));
#pragma unroll
      for (int st = 0; st < 2; ++st)
#pragma unroll
        for (int db = 0; db < 2; ++db)
#pragma unroll
          for (int ks = 0; ks < 2; ++ks)
            vf[st][db][ks] = __builtin_bit_cast(bf16x8,
                *reinterpret_cast<const u32x4*>(vbuf + base + st * 2048 + vfoff[db][ks]));
      chain(kt, dtA, hfA, qf[0], o_[0][0], o_[0][1], l_[0], kf, vf);
      chain(kt, dtB, hfB, qf[1], o_[1][0], o_[1][1], l_[1], kf, vf);
    }
  }

#pragma unroll
  for (int ch = 0; ch < 2; ++ch) {
    const float ltot = l_[ch] + __shfl_xor(l_[ch], 32);
    const float inv = 1.0f / ltot;
    const size_t rowoff = ((size_t)b * Ss + (ch ? q0b : q0a) + l31) * Dd + h * 64;
#pragma unroll
    for (int db = 0; db < 2; ++db)
#pragma unroll
      for (int tt = 0; tt < 4; ++tt) {
        bf16x4 ov;
#pragma unroll
        for (int c = 0; c < 4; ++c) ov[c] = (bf16_t)(o_[ch][db][4 * tt + c] * inv);
        *reinterpret_cast<u32x2*>(&O[rowoff + db * 32 + 8 * tt + 4 * hi]) =
            __builtin_bit_cast(u32x2, ov);
      }
  }
}

// ---------------- launcher ----------------
extern "C" void kernel_launch(void* const* d_in, const int* in_sizes, int n_in,
                              void* d_out, int out_size, void* d_ws, size_t ws_size,
                              hipStream_t stream) {
  (void)in_sizes; (void)n_in; (void)out_size; (void)ws_size;
  const float* x  = (const float*)d_in[0];
  const float* wq = (const float*)d_in[1];
  const float* wk = (const float*)d_in[2];
  const float* wv = (const float*)d_in[3];
  const float* wo = (const float*)d_in[4];
  float* out = (float*)d_out;

  char* ws = (char*)d_ws;
  const size_t MB16 = 16u << 20;
  bf16_t* xb   = (bf16_t*)(ws + 0);          // x bf16; dead after QKV -> AOb
  bf16_t* Qb   = (bf16_t*)(ws + 1 * MB16);
  bf16_t* Kb   = (bf16_t*)(ws + 2 * MB16);
  bf16_t* Vt   = (bf16_t*)(ws + 3 * MB16);   // V written TRANSPOSED by QKV gemm
  bf16_t* wqkv = (bf16_t*)(ws + 4 * MB16);   // [wq;wk;wv;wo] contiguous 8MB
  bf16_t* wob  = wqkv + 3u * Dd * Dd;
  float2* tab  = (float2*)(ws + 4 * MB16 + (8u << 20));  // 512KB cos/sin table
  bf16_t* AOb  = xb;                         // alias: x dead after QKV gemm

  // 1. unified prep (x convert + weight converts + RoPE table)
  prep_k<<<12544, 256, 0, stream>>>(x, wq, wk, wv, wo, xb, wqkv, tab);

  // 2. fused QKV projection (256x256 tile, intensity-64): RoPE on Q (scaled)
  //    and K; V segment written transposed into Vt
  gemm_big<<<dim3(Mm / 256, 12), 1024, 0, stream>>>(xb, wqkv, Qb, Kb, Vt,
                                                    tab, Dd);

  // 3. causal flash attention -> [B,S,D] bf16
  attn_k<<<dim3(8, Bb * Hh), 256, 0, stream>>>(Qb, Kb, Vt, AOb);

  // 4. output projection (fp32 out)
  gemm_r3<<<dim3(Mm / 128, 8), 256, 0, stream>>>(AOb, wob, out, Dd);
}

// Round 17
// 164.544 us; speedup vs baseline: 1.0640x; 1.0640x over previous
//
#include <hip/hip_runtime.h>
#include <hip/hip_bf16.h>
#include <cstdint>
#include <cstddef>

// Problem constants
#define Bb 4
#define Ss 2048
#define Dd 1024
#define Hh 16
#define Mm (Bb*Ss)   // 8192 rows

typedef __bf16 bf16_t;
typedef __bf16 bf16x8 __attribute__((ext_vector_type(8)));
typedef __bf16 bf16x4 __attribute__((ext_vector_type(4)));
typedef float  f32x4  __attribute__((ext_vector_type(4)));
typedef float  f32x16 __attribute__((ext_vector_type(16)));
typedef unsigned int u32x4 __attribute__((ext_vector_type(4)));
typedef unsigned int u32x2 __attribute__((ext_vector_type(2)));

#define MFMA16(a,b,c) __builtin_amdgcn_mfma_f32_16x16x32_bf16(a,b,c,0,0,0)
#define MFMA32(a,b,c) __builtin_amdgcn_mfma_f32_32x32x16_bf16(a,b,c,0,0,0)

#define QSCALE 0.18033688011112042f   // 0.125 * log2(e): exp2-domain softmax

static __device__ __forceinline__ float fexp2(float x) {
#if __has_builtin(__builtin_amdgcn_exp2f)
  return __builtin_amdgcn_exp2f(x);
#else
  return exp2f(x);
#endif
}

static __device__ __forceinline__ bf16x8 ld16g(const bf16_t* p) {
  return __builtin_bit_cast(bf16x8, *reinterpret_cast<const u32x4*>(p));
}

static __device__ __forceinline__ void gload_lds16(const bf16_t* g, bf16_t* l) {
  __builtin_amdgcn_global_load_lds(
      (__attribute__((address_space(1))) void*)(g),
      (__attribute__((address_space(3))) void*)(l),
      16, 0, 0);
}

// ---------- unified prep: x->bf16, weights->bf16 block, RoPE table ----------
// blocks [0,8192): x convert; [8192,12288): weight convert; [12288,12544): tab
__global__ void prep_k(const float* __restrict__ x,  const float* __restrict__ wq,
                       const float* __restrict__ wk, const float* __restrict__ wv,
                       const float* __restrict__ wo,
                       bf16_t* __restrict__ xb, bf16_t* __restrict__ wqkv,
                       float2* __restrict__ tab) {
  int bid = blockIdx.x;
  if (bid < 8192) {
    int i = (bid * 256 + threadIdx.x) * 4;
    float4 f = *reinterpret_cast<const float4*>(x + i);
    xb[i + 0] = (bf16_t)f.x; xb[i + 1] = (bf16_t)f.y;
    xb[i + 2] = (bf16_t)f.z; xb[i + 3] = (bf16_t)f.w;
  } else if (bid < 12288) {
    int b2 = bid - 8192;
    int seg = b2 >> 10, local = b2 & 1023;
    const float* w = (seg == 0) ? wq : (seg == 1) ? wk : (seg == 2) ? wv : wo;
    int i = (local * 256 + threadIdx.x) * 4;
    float4 f = *reinterpret_cast<const float4*>(w + i);
    bf16_t* o = wqkv + (size_t)seg * (Dd * Dd) + i;
    o[0] = (bf16_t)f.x; o[1] = (bf16_t)f.y; o[2] = (bf16_t)f.z; o[3] = (bf16_t)f.w;
  } else {
    int idx = (bid - 12288) * 256 + threadIdx.x;   // 65536
    int i = idx & 31, s = idx >> 5;
    float inv_freq = exp2f(-(float)i * (13.2877123795494f / 32.0f));
    float ang = (float)s * inv_freq;
    float sn, cs;
    sincosf(ang, &sn, &cs);
    tab[idx] = make_float2(cs, sn);
  }
}

// ---------------- GEMM ring3: C[m][n] = sum_k A[m][k]*B[n][k] ---------------
// 128x128 tile, BK=32, 256 thr = 4 waves (2x2), 64x64 per wave; 48KB ring-3
// LDS -> 3 blocks/CU; counted fence vmcnt(4)+lgkmcnt(0)+s_barrier; slot-XOR
// swizzle (0 bank conflicts). Plain 2D grid (round-12/14 best).
// Epilogues: Q segment (n0<1024): RoPE + QSCALE; K segment: RoPE;
// V segment (n0>=2048, VtOut!=null): written TRANSPOSED into Vt[bh][d][s]
// (each lane's 4 acc rows are consecutive s at fixed d -> contiguous 8B) --
// this deletes the separate transpose kernel and its 32MB of traffic.
template <typename OutT>
__global__ __launch_bounds__(256, 3) void gemm_r3(const bf16_t* __restrict__ A,
                                                  const bf16_t* __restrict__ Bm,
                                                  OutT* __restrict__ C0,
                                                  OutT* __restrict__ C1,
                                                  bf16_t* __restrict__ VtOut,
                                                  const float2* __restrict__ tab,
                                                  int Kdim) {
  __shared__ bf16_t As[3][128 * 32];   // 24 KB
  __shared__ bf16_t Bs[3][128 * 32];   // 24 KB
  const int t = threadIdx.x;
  const int lane = t & 63, w = t >> 6;
  const int l15 = lane & 15, lg = lane >> 4;
  const int wr = w >> 1, wc = w & 1;
  const int m0 = blockIdx.x * 128, n0 = blockIdx.y * 128;

  // stage addressing: tile = 128 rows x 32 cols = 512 16B-chunks, 2/thread.
  // chunk q -> row = q>>2, phys slot = q&3, src slot = (q&3)^((row>>1)&3)
  const bf16_t* gA[2];
  const bf16_t* gB[2];
#pragma unroll
  for (int i = 0; i < 2; ++i) {
    int q = i * 256 + t, row = q >> 2, sl = (q & 3) ^ ((row >> 1) & 3);
    gA[i] = A  + (size_t)(m0 + row) * Kdim + sl * 8;
    gB[i] = Bm + (size_t)(n0 + row) * Kdim + sl * 8;
  }
  const int wb = w * 64 * 8;   // wave-uniform LDS elem base (lane*16B added by HW)

  auto stage = [&](int slot, int k0) {
#pragma unroll
    for (int i = 0; i < 2; ++i) {
      gload_lds16(gA[i] + k0, &As[slot][i * 2048 + wb]);
      gload_lds16(gB[i] + k0, &Bs[slot][i * 2048 + wb]);
    }
  };

  // fragment read offsets (elems)
  int aoff[4], boff[4];
#pragma unroll
  for (int i = 0; i < 4; ++i) {
    int row = wr * 64 + i * 16 + l15;
    aoff[i] = row * 32 + ((lg ^ ((row >> 1) & 3)) * 8);
  }
#pragma unroll
  for (int j = 0; j < 4; ++j) {
    int row = wc * 64 + j * 16 + l15;
    boff[j] = row * 32 + ((lg ^ ((row >> 1) & 3)) * 8);
  }

  f32x4 acc[4][4] = {};
  const int KT = Kdim / 32;

  stage(0, 0);
  stage(1, 32);
  for (int j = 0; j < KT; ++j) {
    if (j == KT - 1) {
      asm volatile("s_waitcnt vmcnt(0) lgkmcnt(0)" ::: "memory");
    } else {
      asm volatile("s_waitcnt vmcnt(4) lgkmcnt(0)" ::: "memory");
    }
    __builtin_amdgcn_s_barrier();
    if (j + 2 < KT) stage((j + 2) % 3, (j + 2) * 32);
    const bf16_t* ab = As[j % 3];
    const bf16_t* bb = Bs[j % 3];
    bf16x8 a[4], b[4];
#pragma unroll
    for (int jj = 0; jj < 4; ++jj)
      b[jj] = __builtin_bit_cast(bf16x8,
               *reinterpret_cast<const u32x4*>(bb + boff[jj]));
#pragma unroll
    for (int i = 0; i < 4; ++i)
      a[i] = __builtin_bit_cast(bf16x8,
               *reinterpret_cast<const u32x4*>(ab + aoff[i]));
    __builtin_amdgcn_s_setprio(1);
#pragma unroll
    for (int i = 0; i < 4; ++i)
#pragma unroll
      for (int jj = 0; jj < 4; ++jj)
        acc[i][jj] = MFMA16(a[i], b[jj], acc[i][jj]);
    __builtin_amdgcn_s_setprio(0);
  }

  // epilogue: row = m0 + wr*64 + i*16 + lg*4 + r; col = n0 + wc*64 + j*16 + l15
  const int nb = n0 & 1023;
  if (VtOut != nullptr && n0 >= 2048) {
    // V segment: transposed write Vt[(b*16+h)*64 + d][s], s = row & 2047
#pragma unroll
    for (int i = 0; i < 4; ++i) {
      int rowb = m0 + wr * 64 + i * 16 + lg * 4;
      int b = rowb >> 11, s = rowb & 2047;
#pragma unroll
      for (int j = 0; j < 4; ++j) {
        int col = nb + wc * 64 + j * 16 + l15;
        int h = col >> 6, d = col & 63;
        bf16x4 ov;
#pragma unroll
        for (int r = 0; r < 4; ++r) ov[r] = (bf16_t)acc[i][j][r];
        *reinterpret_cast<u32x2*>(
            &VtOut[(((size_t)(b * 16 + h)) * 64 + d) * 2048 + s]) =
            __builtin_bit_cast(u32x2, ov);
      }
    }
    return;
  }
  OutT* Cs = (n0 < 1024) ? C0 : C1;
  const bool doRope = (tab != nullptr) && (n0 < 2048);
  const float qs = (n0 < 1024) ? QSCALE : 1.0f;

  if (doRope) {
#pragma unroll
    for (int i = 0; i < 4; ++i) {
      int rowb = m0 + wr * 64 + i * 16 + lg * 4;
#pragma unroll
      for (int j = 0; j < 4; ++j) {
        int col = nb + wc * 64 + j * 16 + l15;
        int i0 = (col & 63) >> 1;
        const bool ev = !(col & 1);
#pragma unroll
        for (int r = 0; r < 4; ++r) {
          float v = acc[i][j][r];
          float px = __shfl_xor(v, 1);
          int s = (rowb + r) & (Ss - 1);
          float2 f = tab[s * 32 + i0];
          float sn = ev ? -f.y : f.y;
          Cs[(size_t)(rowb + r) * 1024 + col] = (OutT)((f.x * v + sn * px) * qs);
        }
      }
    }
  } else {
#pragma unroll
    for (int i = 0; i < 4; ++i) {
      int rowb = m0 + wr * 64 + i * 16 + lg * 4;
#pragma unroll
      for (int j = 0; j < 4; ++j) {
        int col = nb + wc * 64 + j * 16 + l15;
#pragma unroll
        for (int r = 0; r < 4; ++r)
          Cs[(size_t)(rowb + r) * 1024 + col] = (OutT)acc[i][j][r];
      }
    }
  }
}

// ---------------- Flash attention (causal, static softmax, KVBLK=128) -------
// grid (8, B*H), 256 thr = 4 waves. Wave i = bx*4+w handles q-chunks 32*i and
// 2016-32*i. K/V staged per 128-key tile into a ring-2 LDS (64KB = exactly
// 2 blocks/CU); fence = vmcnt(0)+lgkmcnt(0)+s_barrier once per 128 keys
// (drained loads were issued a full iteration (~2000cy) earlier -> near-zero
// wait). NT=32-2bx always even -> NT2=16-bx, no odd tail. STATIC softmax
// (p = exp2(s') directly). Swapped QK^T with sigma-permuted K rows keeps P
// in-register feeding PV.
__global__ __launch_bounds__(256, 2) void attn_k(const bf16_t* __restrict__ Q,
                                                 const bf16_t* __restrict__ K,
                                                 const bf16_t* __restrict__ Vt,
                                                 bf16_t* __restrict__ O) {
  __shared__ bf16_t Ks[2][8192];   // [buf][4 subtiles x 16 rows x 128 elems]
  __shared__ bf16_t Vs[2][8192];
  const int t = threadIdx.x, lane = t & 63, w = t >> 6;
  const int l31 = lane & 31, hi = lane >> 5, hi8 = hi * 8;
  const int bh = blockIdx.y, b = bh >> 4, h = bh & 15;
  const int bx = blockIdx.x;
  const int i = bx * 4 + w;                      // 0..31
  const int q0a = 32 * i, q0b = 2016 - 32 * i;
  const int dtA = q0a >> 6, hfA = (q0a >> 5) & 1;
  const int dtB = q0b >> 6, hfB = (q0b >> 5) & 1;
  const int NT2 = 16 - bx;                       // 128-key iterations
  const bf16_t* qb = Q + (size_t)b * Ss * Dd + h * 64;
  const bf16_t* kb = K + (size_t)b * Ss * Dd + h * 64;
  const bf16_t* vtb = Vt + (size_t)bh * 64 * Ss;

  // sigma row permute (A-row r holds key sig(r))
  const int a_ = l31 >> 2, c_ = l31 & 3;
  const int tau = (a_ >> 1) + 2 * (a_ & 1) + ((a_ & 4) >> 1);
  const int sig = c_ + 4 * tau;

  // LDS read offsets (elems, within one 2048-elem subtile)
  int kfoff[4];
#pragma unroll
  for (int c = 0; c < 4; ++c) {
    int j = sig >> 1, u = (sig & 1) * 8 + c * 2 + hi;
    kfoff[c] = j * 128 + ((u ^ j) * 8);
  }
  int vfoff[2][2];
#pragma unroll
  for (int db = 0; db < 2; ++db)
#pragma unroll
    for (int ks = 0; ks < 2; ++ks) {
      int d = db * 32 + l31, j = d >> 2, u = (d & 3) * 4 + ks * 2 + hi;
      vfoff[db][ks] = j * 128 + ((u ^ j) * 8);
    }

  // stage source addressing
  const int sj = t >> 4, ss = t & 15, su = ss ^ sj;
  const bf16_t* ksrc0 = kb + (size_t)(2 * sj + (su >> 3)) * Dd + (su & 7) * 8;
  const bf16_t* vsrc0 = vtb + (size_t)(4 * sj + (su >> 2)) * Ss + (su & 3) * 8;

  auto stage128 = [&](int buf, int kb0) {
    bf16_t* kd = &Ks[buf][w * 512];
    bf16_t* vd = &Vs[buf][w * 512];
#pragma unroll
    for (int st = 0; st < 4; ++st) {
      gload_lds16(ksrc0 + (size_t)(kb0 + 32 * st) * Dd, kd + st * 2048);
      gload_lds16(vsrc0 + kb0 + 32 * st,                vd + st * 2048);
    }
  };

  // Q fragments (B-operand): row q0+l31, d-cols c*16 + hi8 + {0..7}
  bf16x8 qf[2][4];
#pragma unroll
  for (int c = 0; c < 4; ++c) {
    qf[0][c] = ld16g(qb + (size_t)(q0a + l31) * Dd + c * 16 + hi8);
    qf[1][c] = ld16g(qb + (size_t)(q0b + l31) * Dd + c * 16 + hi8);
  }

  float l_[2] = {0.f, 0.f};            // per-lane partial (hi halves merged at end)
  f32x16 o_[2][2] = {};

  // one 64-key chain step (static softmax: p = exp2(score))
  auto chain = [&](int kt, int dt, int hf, bf16x8 (&qc)[4],
                   f32x16& o0, f32x16& o1, float& lc,
                   bf16x8 (&kf)[2][4], bf16x8 (&vf)[2][2][2]) {
    if (kt > dt) return;
    const bool last = (kt == dt);
    const bool do1 = !(last && hf == 0);
    f32x16 s0 = {}, s1 = {};
    __builtin_amdgcn_s_setprio(1);
    s0 = MFMA32(kf[0][0], qc[0], s0);
    s0 = MFMA32(kf[0][1], qc[1], s0);
    s0 = MFMA32(kf[0][2], qc[2], s0);
    s0 = MFMA32(kf[0][3], qc[3], s0);
    if (do1) {
      s1 = MFMA32(kf[1][0], qc[0], s1);
      s1 = MFMA32(kf[1][1], qc[1], s1);
      s1 = MFMA32(kf[1][2], qc[2], s1);
      s1 = MFMA32(kf[1][3], qc[3], s1);
    }
    __builtin_amdgcn_s_setprio(0);
    if (last) {
      if (hf) {
#pragma unroll
        for (int reg = 0; reg < 16; ++reg) {
          const int koff = (reg & 3) + 4 * (reg >> 2) + 8 * ((reg >> 2) >> 1) + hi8;
          s1[reg] = (koff <= l31) ? s1[reg] : -INFINITY;
        }
      } else {
#pragma unroll
        for (int reg = 0; reg < 16; ++reg) {
          const int koff = (reg & 3) + 4 * (reg >> 2) + 8 * ((reg >> 2) >> 1) + hi8;
          s0[reg] = (koff <= l31) ? s0[reg] : -INFINITY;
        }
      }
    }
    float p0[16], p1[16];
#pragma unroll
    for (int r = 0; r < 16; ++r) p0[r] = fexp2(s0[r]);
    bf16x8 pa0, pa1, pb0, pb1;
#pragma unroll
    for (int r = 0; r < 8; ++r) { pa0[r] = (bf16_t)p0[r]; pa1[r] = (bf16_t)p0[r + 8]; }
    if (do1) {
#pragma unroll
      for (int r = 0; r < 16; ++r) p1[r] = fexp2(s1[r]);
#pragma unroll
      for (int r = 0; r < 8; ++r) { pb0[r] = (bf16_t)p1[r]; pb1[r] = (bf16_t)p1[r + 8]; }
#pragma unroll
      for (int r = 0; r < 16; ++r) p0[r] += p1[r];
    }
#pragma unroll
    for (int st2 = 8; st2 > 0; st2 >>= 1)
#pragma unroll
      for (int r = 0; r < st2; ++r) p0[r] += p0[r + st2];
    lc += p0[0];
    __builtin_amdgcn_s_setprio(1);
    o0 = MFMA32(vf[0][0][0], pa0, o0);
    o0 = MFMA32(vf[0][0][1], pa1, o0);
    o1 = MFMA32(vf[0][1][0], pa0, o1);
    o1 = MFMA32(vf[0][1][1], pa1, o1);
    if (do1) {
      o0 = MFMA32(vf[1][0][0], pb0, o0);
      o0 = MFMA32(vf[1][0][1], pb1, o0);
      o1 = MFMA32(vf[1][1][0], pb0, o1);
      o1 = MFMA32(vf[1][1][1], pb1, o1);
    }
    __builtin_amdgcn_s_setprio(0);
  };

  stage128(0, 0);
  for (int jj = 0; jj < NT2; ++jj) {
    asm volatile("s_waitcnt vmcnt(0) lgkmcnt(0)" ::: "memory");
    __builtin_amdgcn_s_barrier();
    if (jj + 1 < NT2) stage128((jj + 1) & 1, (jj + 1) * 128);
    const bf16_t* kbuf = &Ks[jj & 1][0];
    const bf16_t* vbuf = &Vs[jj & 1][0];
#pragma unroll
    for (int half = 0; half < 2; ++half) {
      const int kt = 2 * jj + half;
      const int base = half * 4096;
      bf16x8 kf[2][4], vf[2][2][2];
#pragma unroll
      for (int st = 0; st < 2; ++st)
#pragma unroll
        for (int c = 0; c < 4; ++c)
          kf[st][c] = __builtin_bit_cast(bf16x8,
              *reinterpret_cast<const u32x4*>(kbuf + base + st * 2048 + kfoff[c]));
#pragma unroll
      for (int st = 0; st < 2; ++st)
#pragma unroll
        for (int db = 0; db < 2; ++db)
#pragma unroll
          for (int ks = 0; ks < 2; ++ks)
            vf[st][db][ks] = __builtin_bit_cast(bf16x8,
                *reinterpret_cast<const u32x4*>(vbuf + base + st * 2048 + vfoff[db][ks]));
      chain(kt, dtA, hfA, qf[0], o_[0][0], o_[0][1], l_[0], kf, vf);
      chain(kt, dtB, hfB, qf[1], o_[1][0], o_[1][1], l_[1], kf, vf);
    }
  }

  // epilogue: q = q0+l31; d = db*32 + 8*tt + 4*hi + c
#pragma unroll
  for (int ch = 0; ch < 2; ++ch) {
    const float ltot = l_[ch] + __shfl_xor(l_[ch], 32);
    const float inv = 1.0f / ltot;
    const size_t rowoff = ((size_t)b * Ss + (ch ? q0b : q0a) + l31) * Dd + h * 64;
#pragma unroll
    for (int db = 0; db < 2; ++db)
#pragma unroll
      for (int tt = 0; tt < 4; ++tt) {
        bf16x4 ov;
#pragma unroll
        for (int c = 0; c < 4; ++c) ov[c] = (bf16_t)(o_[ch][db][4 * tt + c] * inv);
        *reinterpret_cast<u32x2*>(&O[rowoff + db * 32 + 8 * tt + 4 * hi]) =
            __builtin_bit_cast(u32x2, ov);
      }
  }
}

// ---------------- launcher ----------------
extern "C" void kernel_launch(void* const* d_in, const int* in_sizes, int n_in,
                              void* d_out, int out_size, void* d_ws, size_t ws_size,
                              hipStream_t stream) {
  (void)in_sizes; (void)n_in; (void)out_size; (void)ws_size;
  const float* x  = (const float*)d_in[0];
  const float* wq = (const float*)d_in[1];
  const float* wk = (const float*)d_in[2];
  const float* wv = (const float*)d_in[3];
  const float* wo = (const float*)d_in[4];
  float* out = (float*)d_out;

  char* ws = (char*)d_ws;
  const size_t MB16 = 16u << 20;
  bf16_t* xb   = (bf16_t*)(ws + 0);          // x bf16; dead after QKV -> AOb
  bf16_t* Qb   = (bf16_t*)(ws + 1 * MB16);
  bf16_t* Kb   = (bf16_t*)(ws + 2 * MB16);
  bf16_t* Vt   = (bf16_t*)(ws + 3 * MB16);   // V written TRANSPOSED by QKV gemm
  bf16_t* wqkv = (bf16_t*)(ws + 4 * MB16);   // [wq;wk;wv;wo] contiguous 8MB
  bf16_t* wob  = wqkv + 3u * Dd * Dd;
  float2* tab  = (float2*)(ws + 4 * MB16 + (8u << 20));  // 512KB cos/sin table
  bf16_t* AOb  = xb;                         // alias: x dead after QKV gemm

  // 1. unified prep (x convert + weight converts + RoPE table)
  prep_k<<<12544, 256, 0, stream>>>(x, wq, wk, wv, wo, xb, wqkv, tab);

  // 2. fused QKV projection: RoPE epilogue on Q (scaled) and K; V segment
  //    written transposed into Vt (transpose kernel eliminated)
  gemm_r3<bf16_t><<<dim3(Mm / 128, 24), 256, 0, stream>>>(xb, wqkv, Qb, Kb, Vt,
                                                          tab, Dd);

  // 3. causal flash attention -> [B,S,D] bf16
  attn_k<<<dim3(8, Bb * Hh), 256, 0, stream>>>(Qb, Kb, Vt, AOb);

  // 4. output projection (fp32 out, no rope, no Vt)
  gemm_r3<float><<<dim3(Mm / 128, 8), 256, 0, stream>>>(AOb, wob, out, out,
                                                        nullptr, nullptr, Dd);
}